// Round 16
// baseline (1633.089 us; speedup 1.0000x reference)
//
#include <hip/hip_runtime.h>
#include <hip/hip_bf16.h>
#include <cstdint>
#include <cstddef>

// ---------------------------------------------------------------------------
// MiniGPT forward on MI355X (gfx950).  Round 15:
//  - logits 8-phase rotated-quadrant kernel FIXED: per-wave LDS staging
//    offset (wv*8 rows) restored in stA/stB (r14 dropped it -> all 8 waves
//    DMA'd into the same 1KB -> NaN).  Schedule unchanged (fully re-traced).
//  - everything else identical to the passing round-13 build.
// MODES: 0 QKV-split  2 GELU->bf16  3 f32 NT store  6 f32 NT partial (+bias@kz0)
// ---------------------------------------------------------------------------

typedef __attribute__((ext_vector_type(4))) float  f32x4;
typedef __attribute__((ext_vector_type(8))) __bf16 bf16x8;
typedef __attribute__((ext_vector_type(4))) __bf16 bf16x4;

#define S_LEN 2048
#define DMODEL 1024
#define DFF 4096
#define NLAYER 6
#define NHEAD 16
#define DK 64
#define VOCAB 32000
#define MN (S_LEN * DMODEL)

__device__ __forceinline__ void gload_lds16(const void* g, void* l) {
    __builtin_amdgcn_global_load_lds(
        (__attribute__((address_space(1))) void*)(void*)(g),
        (__attribute__((address_space(3))) void*)(l), 16, 0, 0);
}

// ---------------------------------------------------------------------------
// 64x64 transpose+cvt body (shared).
// ---------------------------------------------------------------------------
__device__ __forceinline__ void tr64_body(
    const float* __restrict__ inp, __bf16* __restrict__ outp,
    int K, int N, int n0, int k0, int t) {
    __shared__ float tile[64][65];
    const int lc = t & 15, rr = t >> 4;
#pragma unroll
    for (int i = 0; i < 4; ++i) {
        float4 v = *(const float4*)&inp[(size_t)(k0 + rr + i * 16) * N + n0 + lc * 4];
        tile[rr + i * 16][lc * 4 + 0] = v.x;
        tile[rr + i * 16][lc * 4 + 1] = v.y;
        tile[rr + i * 16][lc * 4 + 2] = v.z;
        tile[rr + i * 16][lc * 4 + 3] = v.w;
    }
    __syncthreads();
    const int a = t & 7, b = t >> 3;
#pragma unroll
    for (int j = 0; j < 2; ++j) {
        const int n = b + j * 32;
        bf16x8 o;
#pragma unroll
        for (int e = 0; e < 8; ++e) o[e] = (__bf16)tile[a * 8 + e][n];
        *(bf16x8*)&outp[(size_t)(n0 + n) * K + k0 + a * 8] = o;
    }
}

__global__ __launch_bounds__(256) void transpose_cvt64(
    const float* __restrict__ in, __bf16* __restrict__ out,
    int K, int N, size_t in_lstride, size_t out_lstride) {
    tr64_body(in + blockIdx.z * in_lstride, out + blockIdx.z * out_lstride,
              K, N, blockIdx.x * 64, blockIdx.y * 64, threadIdx.x);
}

// batched Wq/Wk/Wv/Wo transpose: grid (16,16,4*NLAYER); z -> (mat, layer)
__global__ __launch_bounds__(256) void transpose_qkvo(
    const float* __restrict__ Wq, const float* __restrict__ Wk,
    const float* __restrict__ Wv, const float* __restrict__ Wo,
    __bf16* __restrict__ wqkv_t, __bf16* __restrict__ wo_t) {
    const int z = blockIdx.z, mat = z & 3, l = z >> 2;
    const float* src =
        (mat == 0 ? Wq : mat == 1 ? Wk : mat == 2 ? Wv : Wo) +
        (size_t)l * 1024 * 1024;
    __bf16* dst = (mat < 3)
        ? wqkv_t + (size_t)l * 3072 * 1024 + (size_t)mat * 1024 * 1024
        : wo_t + (size_t)l * 1024 * 1024;
    tr64_body(src, dst, 1024, 1024, blockIdx.x * 64, blockIdx.y * 64, threadIdx.x);
}

__global__ __launch_bounds__(256) void cvt_bf16(
    const float* __restrict__ in, __bf16* __restrict__ out, long n4) {
    long i = (long)blockIdx.x * 256 + threadIdx.x;
    if (i >= n4) return;
    float4 v = ((const float4*)in)[i];
    bf16x4 o = {(__bf16)v.x, (__bf16)v.y, (__bf16)v.z, (__bf16)v.w};
    ((bf16x4*)out)[i] = o;
}

// ---------------------------------------------------------------------------
// LayerNorm family.  EMBED: x = tok_emb[tok]+pos_emb first.  NPART=2: fuse
// x += p[row] + p[MN+row] first.  f32 in, bf16 out.  grid = rows, block 256.
// ---------------------------------------------------------------------------
template <int NPART, int EMBED>
__global__ __launch_bounds__(256) void ln_kernel(
    float* __restrict__ x, const float* __restrict__ p,
    const float* __restrict__ g, const float* __restrict__ b,
    __bf16* __restrict__ out,
    const int* __restrict__ tokens, const float* __restrict__ te,
    const float* __restrict__ pe) {
    const int row = blockIdx.x, t = threadIdx.x;
    float4 v;
    if (EMBED) {
        const int tok = tokens[row];
        float4 a = ((const float4*)(te + (size_t)tok * DMODEL))[t];
        float4 q = ((const float4*)(pe + (size_t)row * DMODEL))[t];
        v = float4{a.x + q.x, a.y + q.y, a.z + q.z, a.w + q.w};
        ((float4*)(x + (size_t)row * DMODEL))[t] = v;
    } else {
        v = ((const float4*)(x + (size_t)row * DMODEL))[t];
    }
    if (NPART == 2) {
        float4 a0 = ((const float4*)(p + (size_t)row * DMODEL))[t];
        float4 a1 = ((const float4*)(p + MN + (size_t)row * DMODEL))[t];
        v.x += a0.x + a1.x;
        v.y += a0.y + a1.y;
        v.z += a0.z + a1.z;
        v.w += a0.w + a1.w;
        ((float4*)(x + (size_t)row * DMODEL))[t] = v;
    }
    float s  = v.x + v.y + v.z + v.w;
    float s2 = v.x * v.x + v.y * v.y + v.z * v.z + v.w * v.w;
#pragma unroll
    for (int off = 1; off < 64; off <<= 1) {
        s  += __shfl_xor(s, off);
        s2 += __shfl_xor(s2, off);
    }
    __shared__ float ss[4], ss2[4];
    const int wave = t >> 6;
    if ((t & 63) == 0) { ss[wave] = s; ss2[wave] = s2; }
    __syncthreads();
    s  = ss[0] + ss[1] + ss[2] + ss[3];
    s2 = ss2[0] + ss2[1] + ss2[2] + ss2[3];
    const float mu  = s * (1.0f / DMODEL);
    const float var = s2 * (1.0f / DMODEL) - mu * mu;
    const float rstd = rsqrtf(var + 1e-5f);
    float4 gg = ((const float4*)g)[t];
    float4 bb = ((const float4*)b)[t];
    __bf16* o = out + (size_t)row * DMODEL + t * 4;
    o[0] = (__bf16)((v.x - mu) * rstd * gg.x + bb.x);
    o[1] = (__bf16)((v.y - mu) * rstd * gg.y + bb.y);
    o[2] = (__bf16)((v.z - mu) * rstd * gg.z + bb.z);
    o[3] = (__bf16)((v.w - mu) * rstd * gg.w + bb.w);
}

// ---------------------------------------------------------------------------
// gemm_tiled<BM,BN,BK,SPLITK,MODE,XCD>: two-barrier counted-vmcnt (round-9).
// ---------------------------------------------------------------------------
template <int BM, int BN, int BK, int SPLITK, int MODE, int XCD>
__global__ __launch_bounds__(256) void gemm_tiled(
    const __bf16* __restrict__ A, const __bf16* __restrict__ BT,
    int M, int N, int K,
    const float* __restrict__ bias,
    float* __restrict__ fout,
    __bf16* __restrict__ bfout,
    __bf16* __restrict__ qb, __bf16* __restrict__ kb, __bf16* __restrict__ vb,
    const float* __restrict__ bq, const float* __restrict__ bk,
    const float* __restrict__ bv) {
    constexpr int SLOTS = BK / 8;
    constexpr int SH    = (BK == 64) ? 0 : 1;
    constexpr int RPC   = 2048 / BK;
    constexpr int ACH_A = BM / RPC;
    constexpr int ACH_B = BN / RPC;
    constexpr int LOADS = ACH_A + ACH_B;
    constexpr int MR = BM / 32;
    constexpr int NR = BN / 32;
    constexpr int KS = BK / 32;
    __shared__ alignas(16) __bf16 As[2][BM * BK];
    __shared__ alignas(16) __bf16 Bs[2][BN * BK];
    const int t = threadIdx.x;
    const int wave = t >> 6, lane = t & 63;
    const int wr = wave >> 1, wc = wave & 1;
    const int lg = lane >> 4, lr = lane & 15;

    int bx = blockIdx.x, by = blockIdx.y;
    if (XCD) {
        const int nwg = gridDim.x * gridDim.y;
        const int wgid = by * gridDim.x + bx;
        const int sw = (wgid & 7) * (nwg >> 3) + (wgid >> 3);
        bx = sw % gridDim.x;
        by = sw / gridDim.x;
    }
    const int row0 = bx * BM, col0 = by * BN;
    const int kz = (SPLITK > 1) ? blockIdx.z : 0;
    const int Ksl = K / SPLITK;

    f32x4 acc[MR][NR];
#pragma unroll
    for (int i = 0; i < MR; i++)
#pragma unroll
        for (int j = 0; j < NR; j++) acc[i][j] = f32x4{0.f, 0.f, 0.f, 0.f};

    const int srow = t / SLOTS;
    const int sks = ((t % SLOTS) ^ ((srow >> SH) & (SLOTS - 1))) * 8;
    const __bf16* Ab = A + (size_t)(row0 + srow) * K + kz * Ksl + sks;
    const __bf16* Bb = BT + (size_t)(col0 + srow) * K + kz * Ksl + sks;

    const int nt = Ksl / BK;
#pragma unroll
    for (int ch = 0; ch < ACH_A; ++ch)
        gload_lds16(Ab + (size_t)ch * RPC * K, &As[0][ch * 2048 + wave * 512]);
#pragma unroll
    for (int ch = 0; ch < ACH_B; ++ch)
        gload_lds16(Bb + (size_t)ch * RPC * K, &Bs[0][ch * 2048 + wave * 512]);

    int c = 0;
    for (int T = 0; T < nt; ++T) {
        if (T + 1 < nt) {
            const int k0 = (T + 1) * BK;
#pragma unroll
            for (int ch = 0; ch < ACH_A; ++ch)
                gload_lds16(Ab + (size_t)ch * RPC * K + k0,
                            &As[c ^ 1][ch * 2048 + wave * 512]);
#pragma unroll
            for (int ch = 0; ch < ACH_B; ++ch)
                gload_lds16(Bb + (size_t)ch * RPC * K + k0,
                            &Bs[c ^ 1][ch * 2048 + wave * 512]);
            if constexpr (LOADS == 3)
                asm volatile("s_waitcnt vmcnt(3)" ::: "memory");
            else if constexpr (LOADS == 4)
                asm volatile("s_waitcnt vmcnt(4)" ::: "memory");
            else if constexpr (LOADS == 6)
                asm volatile("s_waitcnt vmcnt(6)" ::: "memory");
            else
                asm volatile("s_waitcnt vmcnt(8)" ::: "memory");
        } else {
            asm volatile("s_waitcnt vmcnt(0)" ::: "memory");
        }
        __builtin_amdgcn_s_barrier();
        asm volatile("" ::: "memory");

        bf16x8 af[MR][KS], bfr[NR][KS];
#pragma unroll
        for (int i = 0; i < MR; i++)
#pragma unroll
            for (int ks = 0; ks < KS; ks++) {
                const int row = wr * (BM / 2) + i * 16 + lr;
                const int ph = ((ks * 4 + lg) ^ ((row >> SH) & (SLOTS - 1)));
                af[i][ks] = *(const bf16x8*)&As[c][row * BK + ph * 8];
            }
#pragma unroll
        for (int j = 0; j < NR; j++)
#pragma unroll
            for (int ks = 0; ks < KS; ks++) {
                const int n = wc * (BN / 2) + j * 16 + lr;
                const int ph = ((ks * 4 + lg) ^ ((n >> SH) & (SLOTS - 1)));
                bfr[j][ks] = *(const bf16x8*)&Bs[c][n * BK + ph * 8];
            }
        __builtin_amdgcn_s_setprio(1);
#pragma unroll
        for (int i = 0; i < MR; i++)
#pragma unroll
            for (int j = 0; j < NR; j++)
#pragma unroll
                for (int ks = 0; ks < KS; ks++)
                    acc[i][j] = __builtin_amdgcn_mfma_f32_16x16x32_bf16(
                        af[i][ks], bfr[j][ks], acc[i][j], 0, 0, 0);
        __builtin_amdgcn_s_setprio(0);
        asm volatile("" ::: "memory");
        __builtin_amdgcn_s_barrier();
        c ^= 1;
    }

#pragma unroll
    for (int i = 0; i < MR; i++) {
#pragma unroll
        for (int j = 0; j < NR; j++) {
#pragma unroll
            for (int r = 0; r < 4; r++) {
                const int row = row0 + wr * (BM / 2) + i * 16 + lg * 4 + r;
                const int col = col0 + wc * (BN / 2) + j * 16 + lr;
                float v = acc[i][j][r];
                if (MODE == 0) {          // fused QKV split epilogue
                    const int sec = col >> 10, cn = col & 1023;
                    const int head = cn >> 6, d = cn & 63;
                    if (sec == 0) {
                        // fold 1/sqrt(dk) * log2(e): softmax in exp2 domain
                        v = (v + bq[cn]) * 0.18033688011112042f;
                        qb[((size_t)head * S_LEN + row) * DK + d] = (__bf16)v;
                    } else if (sec == 1) {
                        v = v + bk[cn];
                        kb[((size_t)head * S_LEN + row) * DK + d] = (__bf16)v;
                    } else {
                        v = v + bv[cn];
                        vb[((size_t)head * DK + d) * S_LEN + row] = (__bf16)v;
                    }
                } else if (MODE == 2) {
                    const float gg = v + bias[col];
                    const float cgl = 0.5f * gg * (1.0f + erff(gg * 0.70710678118654752f));
                    bfout[(size_t)row * N + col] = (__bf16)cgl;
                } else if (MODE == 6) {   // split-K partial, bias on slice 0
                    const float vv = v + (kz == 0 ? bias[col] : 0.f);
                    __builtin_nontemporal_store(
                        vv, &fout[(size_t)kz * MN + (size_t)row * N + col]);
                } else {                  // MODE 3: plain f32 NT store
                    __builtin_nontemporal_store(v, &fout[(size_t)row * N + col]);
                }
            }
        }
    }
}

// ---------------------------------------------------------------------------
// Logits GEMM, 8-phase rotated-quadrant 256x256 kernel (r14 + staging fix).
// M=2048 N=32000 K=1024 (NT=16 K-tiles of BK=64).  512 thr = 8 waves.
// LDS: 2 buf x (A 32KB + B 32KB) = 128 KiB.  Halves: A0/A1 rows 0-127/128-255,
// B0/B1 cols 0-127/128-255; each half = 2 gload_lds per wave, wave wv owns
// rows [hf*128 + wv*8, +8) and [hf*128 + 64 + wv*8, +8).
// Per phase ALL 8 waves compute one (A-half x B-half) 128x128 block, split
// 2x4 (pm=wv>>2, pn=wv&3).  Phase order (0,0)->(1,0)->(1,1)->(0,1); af
// reused (1,0)->(1,1), bfr reused (0,0)->(1,0) and (1,1)->(0,1).
// Per-wave queue trace (steady state; 2 loads per stage call):
//   enter q0: {A1,B1}=4 in flight; q0 reads A0,B0 (landed), stage A0';
//     end-q0 vmcnt(4) completes A1 -> barrier.
//   q1 reads A1, stage B0'; end-q1 vmcnt(4) completes B1 -> barrier.
//   q2 reads B1, stage A1'; NO wait/barrier (q3 reads only resident data;
//     staging targets the other buffer).
//   q3 reads A0 (resident), stage B1'; end-q3 vmcnt(4) completes A0',B0'
//     -> barrier -> next tile.
// Tail (T=15, no staging): end-q0 vmcnt(2); end-q1 vmcnt(0).
// Counted waits precede each barrier -> cross-wave LDS visibility sound.
// K-accumulation order identical to 2-phase kernel -> bitwise-same logits.
// Swizzle slot^(row&7) both sides (row&7 == l>>3 on write side).  XCD grid.
// ---------------------------------------------------------------------------
__global__ __launch_bounds__(512, 1) void gemm_logits_8r(
    const __bf16* __restrict__ A, const __bf16* __restrict__ BT,
    float* __restrict__ fout) {
    constexpr int K = 1024, N = VOCAB, NT = 16;
    __shared__ alignas(16) __bf16 As[2][256 * 64];
    __shared__ alignas(16) __bf16 Bs[2][256 * 64];
    const int t = threadIdx.x;
    const int wv = t >> 6, lane = t & 63;
    const int pm = wv >> 2, pn = wv & 3;
    const int lg = lane >> 4, lr = lane & 15;

    const int wgid = blockIdx.x;
    const int sw = (wgid & 7) * 125 + (wgid >> 3);   // bijective (1000=8*125)
    const int row0 = (sw & 7) * 256;
    const int col0 = (sw >> 3) * 256;

    const int srow = t >> 3;                       // 0..63 (wave wv: 8wv..8wv+7)
    const int sks = ((t & 7) ^ (srow & 7)) * 8;    // pre-swizzled source k
    const __bf16* Ab = A + (size_t)(row0 + srow) * K + sks;
    const __bf16* Bb = BT + (size_t)(col0 + srow) * K + sks;

    auto stA = [&](int T, int hf) {   // A rows [hf*128, +128) of tile T
        const __bf16* g = Ab + (size_t)(hf * 128) * K + T * 64;
        gload_lds16(g, &As[T & 1][(hf * 128 + wv * 8) * 64]);
        gload_lds16(g + (size_t)64 * K, &As[T & 1][(hf * 128 + 64 + wv * 8) * 64]);
    };
    auto stB = [&](int T, int hf) {   // B cols [hf*128, +128) of tile T
        const __bf16* g = Bb + (size_t)(hf * 128) * K + T * 64;
        gload_lds16(g, &Bs[T & 1][(hf * 128 + wv * 8) * 64]);
        gload_lds16(g + (size_t)64 * K, &Bs[T & 1][(hf * 128 + 64 + wv * 8) * 64]);
    };

    // acc[pt][il][jl]: pt -> (ah,bh) in {(0,0),(1,0),(1,1),(0,1)}
    f32x4 acc[4][4][2];
#pragma unroll
    for (int p = 0; p < 4; p++)
#pragma unroll
        for (int i = 0; i < 4; i++)
#pragma unroll
            for (int j = 0; j < 2; j++) acc[p][i][j] = f32x4{0.f, 0.f, 0.f, 0.f};

    bf16x8 af[4][2], bfr[2][2];
    auto loadA = [&](int b, int ah) {
#pragma unroll
        for (int il = 0; il < 4; il++)
#pragma unroll
            for (int ks = 0; ks < 2; ks++) {
                const int row = ah * 128 + pm * 64 + il * 16 + lr;
                af[il][ks] = *(const bf16x8*)
                    &As[b][row * 64 + (((ks * 4 + lg) ^ (row & 7)) * 8)];
            }
    };
    auto loadB = [&](int b, int bh) {
#pragma unroll
        for (int jl = 0; jl < 2; jl++)
#pragma unroll
            for (int ks = 0; ks < 2; ks++) {
                const int n = bh * 128 + pn * 32 + jl * 16 + lr;
                bfr[jl][ks] = *(const bf16x8*)
                    &Bs[b][n * 64 + (((ks * 4 + lg) ^ (n & 7)) * 8)];
            }
    };

    // prologue: all 4 halves of tile 0 (queue=8/wave); need A0,B0 -> vmcnt(4)
    stA(0, 0); stB(0, 0); stA(0, 1); stB(0, 1);
    asm volatile("s_waitcnt vmcnt(4)" ::: "memory");
    __builtin_amdgcn_s_barrier();
    asm volatile("" ::: "memory");

    for (int T = 0; T < NT; ++T) {
        const int b = T & 1;
        const bool pf = (T + 1 < NT);

        // ---- q0: (A0 x B0) -> acc[0]; stage A0(T+1) ----
        loadA(b, 0); loadB(b, 0);
        if (pf) stA(T + 1, 0);
        __builtin_amdgcn_s_setprio(1);
#pragma unroll
        for (int il = 0; il < 4; il++)
#pragma unroll
            for (int jl = 0; jl < 2; jl++)
#pragma unroll
                for (int ks = 0; ks < 2; ks++)
                    acc[0][il][jl] = __builtin_amdgcn_mfma_f32_16x16x32_bf16(
                        af[il][ks], bfr[jl][ks], acc[0][il][jl], 0, 0, 0);
        __builtin_amdgcn_s_setprio(0);
        if (pf) asm volatile("s_waitcnt vmcnt(4)" ::: "memory");
        else    asm volatile("s_waitcnt vmcnt(2)" ::: "memory");
        __builtin_amdgcn_s_barrier();
        asm volatile("" ::: "memory");

        // ---- q1: (A1 x B0) -> acc[1]; bfr reused; stage B0(T+1) ----
        loadA(b, 1);
        if (pf) stB(T + 1, 0);
        __builtin_amdgcn_s_setprio(1);
#pragma unroll
        for (int il = 0; il < 4; il++)
#pragma unroll
            for (int jl = 0; jl < 2; jl++)
#pragma unroll
                for (int ks = 0; ks < 2; ks++)
                    acc[1][il][jl] = __builtin_amdgcn_mfma_f32_16x16x32_bf16(
                        af[il][ks], bfr[jl][ks], acc[1][il][jl], 0, 0, 0);
        __builtin_amdgcn_s_setprio(0);
        if (pf) asm volatile("s_waitcnt vmcnt(4)" ::: "memory");
        else    asm volatile("s_waitcnt vmcnt(0)" ::: "memory");
        __builtin_amdgcn_s_barrier();
        asm volatile("" ::: "memory");

        // ---- q2: (A1 x B1) -> acc[2]; af reused; stage A1(T+1) ----
        loadB(b, 1);
        if (pf) stA(T + 1, 1);
        __builtin_amdgcn_s_setprio(1);
#pragma unroll
        for (int il = 0; il < 4; il++)
#pragma unroll
            for (int jl = 0; jl < 2; jl++)
#pragma unroll
                for (int ks = 0; ks < 2; ks++)
                    acc[2][il][jl] = __builtin_amdgcn_mfma_f32_16x16x32_bf16(
                        af[il][ks], bfr[jl][ks], acc[2][il][jl], 0, 0, 0);
        __builtin_amdgcn_s_setprio(0);
        // q3 consumes only resident data; staging targets the other buffer:
        // no wait, no barrier here.

        // ---- q3: (A0 x B1) -> acc[3]; bfr reused; stage B1(T+1) ----
        loadA(b, 0);
        if (pf) stB(T + 1, 1);
        __builtin_amdgcn_s_setprio(1);
#pragma unroll
        for (int il = 0; il < 4; il++)
#pragma unroll
            for (int jl = 0; jl < 2; jl++)
#pragma unroll
                for (int ks = 0; ks < 2; ks++)
                    acc[3][il][jl] = __builtin_amdgcn_mfma_f32_16x16x32_bf16(
                        af[il][ks], bfr[jl][ks], acc[3][il][jl], 0, 0, 0);
        __builtin_amdgcn_s_setprio(0);
        if (pf) {
            asm volatile("s_waitcnt vmcnt(4)" ::: "memory");
            __builtin_amdgcn_s_barrier();
            asm volatile("" ::: "memory");
        }
    }

    // epilogue: pt -> (ah,bh) = {(0,0),(1,0),(1,1),(0,1)}
#pragma unroll
    for (int p = 0; p < 4; p++) {
        const int ah = (p == 1 || p == 2) ? 1 : 0;
        const int bh = (p >= 2) ? 1 : 0;
#pragma unroll
        for (int il = 0; il < 4; il++)
#pragma unroll
            for (int jl = 0; jl < 2; jl++)
#pragma unroll
                for (int r = 0; r < 4; r++) {
                    const int row = row0 + ah * 128 + pm * 64 + il * 16 + lg * 4 + r;
                    const int col = col0 + bh * 128 + pn * 32 + jl * 16 + lr;
                    __builtin_nontemporal_store(acc[p][il][jl][r],
                                                &fout[(size_t)row * N + col]);
                }
    }
}

// ---------------------------------------------------------------------------
// Flash attention (causal).  grid (32, NHEAD), block 256 (4 independent
// waves).  XCD head-clustering (each XCD owns 2 heads -> K/V L2-resident).
// Wave w handles q-rowgroup {2x,2x+1,126-2x,127-2x}[w] -> uniform work.
// KVBLK=128; scores pre-scaled by log2e/8 -> exp2 softmax.
// ---------------------------------------------------------------------------
__global__ __launch_bounds__(256) void attn_kernel(
    const __bf16* __restrict__ q, const __bf16* __restrict__ k,
    const __bf16* __restrict__ vt, __bf16* __restrict__ ctx) {
    const int lin = blockIdx.y * 32 + blockIdx.x;
    const int u = (lin & 7) * 64 + (lin >> 3);   // XCD c -> heads {2c, 2c+1}
    const int head = u >> 5, xb = u & 31;
    const int t = threadIdx.x;
    const int wave = t >> 6, lane = t & 63;
    const int lg = lane >> 4, lr = lane & 15;
    const int rg = (wave < 2) ? (2 * xb + wave) : (127 - 2 * xb - (3 - wave));
    const int rowbase = rg * 16;
    const int tend = rg >> 3;

    const __bf16* qh = q + (size_t)head * S_LEN * DK;
    const __bf16* kh = k + (size_t)head * S_LEN * DK;
    const __bf16* vh = vt + (size_t)head * DK * S_LEN;

    __shared__ alignas(16) __bf16 pls[4][16 * 136];
    __bf16* pw = pls[wave];

    bf16x8 qf0 = *(const bf16x8*)&qh[(size_t)(rowbase + lr) * DK + lg * 8];
    bf16x8 qf1 = *(const bf16x8*)&qh[(size_t)(rowbase + lr) * DK + 32 + lg * 8];

    f32x4 oacc[4];
#pragma unroll
    for (int j = 0; j < 4; j++) oacc[j] = f32x4{0.f, 0.f, 0.f, 0.f};
    float m[4], l[4];
#pragma unroll
    for (int r = 0; r < 4; r++) { m[r] = -__builtin_inff(); l[r] = 0.f; }

    for (int tt = 0; tt <= tend; ++tt) {
        const int kv0 = tt * 128;
        f32x4 sc[8];
        __builtin_amdgcn_s_setprio(1);
#pragma unroll
        for (int jn = 0; jn < 8; jn++) {
            bf16x8 kf0 = *(const bf16x8*)&kh[(size_t)(kv0 + jn * 16 + lr) * DK + lg * 8];
            bf16x8 kf1 = *(const bf16x8*)&kh[(size_t)(kv0 + jn * 16 + lr) * DK + 32 + lg * 8];
            sc[jn] = __builtin_amdgcn_mfma_f32_16x16x32_bf16(
                qf0, kf0, f32x4{0.f, 0.f, 0.f, 0.f}, 0, 0, 0);
            sc[jn] = __builtin_amdgcn_mfma_f32_16x16x32_bf16(qf1, kf1, sc[jn], 0, 0, 0);
        }
        __builtin_amdgcn_s_setprio(0);

        if (tt == tend) {
#pragma unroll
            for (int jn = 0; jn < 8; jn++)
#pragma unroll
                for (int r = 0; r < 4; r++) {
                    const int qrow = rowbase + lg * 4 + r;
                    if (kv0 + jn * 16 + lr > qrow) sc[jn][r] = -__builtin_inff();
                }
        }

        float mt[4];
#pragma unroll
        for (int r = 0; r < 4; r++) {
            float a0 = fmaxf(fmaxf(sc[0][r], sc[1][r]), fmaxf(sc[2][r], sc[3][r]));
            float a1 = fmaxf(fmaxf(sc[4][r], sc[5][r]), fmaxf(sc[6][r], sc[7][r]));
            mt[r] = fmaxf(a0, a1);
        }
#pragma unroll
        for (int off = 1; off < 16; off <<= 1)
#pragma unroll
            for (int r = 0; r < 4; r++) mt[r] = fmaxf(mt[r], __shfl_xor(mt[r], off));

        float alpha[4], psum[4];
#pragma unroll
        for (int r = 0; r < 4; r++) {
            const float mn = fmaxf(m[r], mt[r]);
            alpha[r] = exp2f(m[r] - mn);
            m[r] = mn;
#pragma unroll
            for (int jn = 0; jn < 8; jn++) sc[jn][r] = exp2f(sc[jn][r] - mn);
            psum[r] = ((sc[0][r] + sc[1][r]) + (sc[2][r] + sc[3][r])) +
                      ((sc[4][r] + sc[5][r]) + (sc[6][r] + sc[7][r]));
        }
#pragma unroll
        for (int off = 1; off < 16; off <<= 1)
#pragma unroll
            for (int r = 0; r < 4; r++) psum[r] += __shfl_xor(psum[r], off);
#pragma unroll
        for (int r = 0; r < 4; r++) l[r] = l[r] * alpha[r] + psum[r];
#pragma unroll
        for (int j = 0; j < 4; j++)
#pragma unroll
            for (int r = 0; r < 4; r++) oacc[j][r] *= alpha[r];

#pragma unroll
        for (int r = 0; r < 4; r++)
#pragma unroll
            for (int jn = 0; jn < 8; jn++)
                pw[(lg * 4 + r) * 136 + jn * 16 + lr] = (__bf16)sc[jn][r];

        bf16x8 pf[4];
#pragma unroll
        for (int h = 0; h < 4; h++)
            pf[h] = *(const bf16x8*)&pw[lr * 136 + h * 32 + lg * 8];
        __builtin_amdgcn_s_setprio(1);
#pragma unroll
        for (int j = 0; j < 4; j++) {
#pragma unroll
            for (int h = 0; h < 4; h++) {
                bf16x8 vf = *(const bf16x8*)
                    &vh[(size_t)(j * 16 + lr) * S_LEN + kv0 + h * 32 + lg * 8];
                oacc[j] = __builtin_amdgcn_mfma_f32_16x16x32_bf16(
                    pf[h], vf, oacc[j], 0, 0, 0);
            }
        }
        __builtin_amdgcn_s_setprio(0);
    }

#pragma unroll
    for (int j = 0; j < 4; j++)
#pragma unroll
        for (int r = 0; r < 4; r++) {
            const int row = rowbase + lg * 4 + r;
            ctx[(size_t)row * DMODEL + head * DK + j * 16 + lr] =
                (__bf16)(oacc[j][r] / l[r]);
        }
}

// ---------------------------------------------------------------------------
extern "C" void kernel_launch(void* const* d_in, const int* in_sizes, int n_in,
                              void* d_out, int out_size, void* d_ws, size_t ws_size,
                              hipStream_t stream) {
    const int*   tokens  = (const int*)d_in[0];
    const float* tok_emb = (const float*)d_in[1];
    const float* pos_emb = (const float*)d_in[2];
    const float* Wq = (const float*)d_in[3];
    const float* bq = (const float*)d_in[4];
    const float* Wk = (const float*)d_in[5];
    const float* bk = (const float*)d_in[6];
    const float* Wv = (const float*)d_in[7];
    const float* bv = (const float*)d_in[8];
    const float* Wo = (const float*)d_in[9];
    const float* bo = (const float*)d_in[10];
    const float* ln1_g = (const float*)d_in[11];
    const float* ln1_b = (const float*)d_in[12];
    const float* ln2_g = (const float*)d_in[13];
    const float* ln2_b = (const float*)d_in[14];
    const float* W1 = (const float*)d_in[15];
    const float* b1 = (const float*)d_in[16];
    const float* W2 = (const float*)d_in[17];
    const float* b2 = (const float*)d_in[18];
    const float* lnf_g = (const float*)d_in[19];
    const float* lnf_b = (const float*)d_in[20];

    char* ws = (char*)d_ws;
    size_t off = 0;
    auto alloc = [&](size_t bytes) {
        char* p = ws + off;
        off = (off + bytes + 255) & ~(size_t)255;
        return p;
    };
    __bf16* wqkv_t = (__bf16*)alloc((size_t)NLAYER * 3072 * 1024 * 2);
    __bf16* wo_t   = (__bf16*)alloc((size_t)NLAYER * 1024 * 1024 * 2);
    __bf16* w1_t   = (__bf16*)alloc((size_t)NLAYER * 4096 * 1024 * 2);
    __bf16* w2_t   = (__bf16*)alloc((size_t)NLAYER * 1024 * 4096 * 2);
    __bf16* temb   = (__bf16*)alloc((size_t)VOCAB * DMODEL * 2);
    float*  x      = (float*)alloc((size_t)MN * 4);
    __bf16* h      = (__bf16*)alloc((size_t)MN * 2);
    __bf16* qbuf   = (__bf16*)alloc((size_t)MN * 2);
    __bf16* kbuf   = (__bf16*)alloc((size_t)MN * 2);
    __bf16* vbuf   = (__bf16*)alloc((size_t)MN * 2);
    __bf16* ctx    = (__bf16*)alloc((size_t)MN * 2);
    __bf16* ffn    = (__bf16*)alloc((size_t)S_LEN * DFF * 2);
    if (off > ws_size) return;

    // split-K partial overlays (dead regions during their live windows)
    float* pproj  = (float*)ffn;      // dead until FFN1 writes it
    float* pffn2  = (float*)qbuf;     // q/k/v/ctx dead after proj

    const dim3 blk256(256);

    transpose_qkvo<<<dim3(16, 16, 4 * NLAYER), blk256, 0, stream>>>(
        Wq, Wk, Wv, Wo, wqkv_t, wo_t);
    transpose_cvt64<<<dim3(64, 16, NLAYER), blk256, 0, stream>>>(
        W1, w1_t, 1024, 4096, (size_t)1024 * 4096, (size_t)4096 * 1024);
    transpose_cvt64<<<dim3(16, 64, NLAYER), blk256, 0, stream>>>(
        W2, w2_t, 4096, 1024, (size_t)4096 * 1024, (size_t)1024 * 4096);
    cvt_bf16<<<dim3((VOCAB * DMODEL / 4 + 255) / 256), blk256, 0, stream>>>(
        tok_emb, temb, (long)VOCAB * DMODEL / 4);

    // fused embed + LN1(layer 0)
    ln_kernel<0, 1><<<dim3(S_LEN), blk256, 0, stream>>>(
        x, nullptr, ln1_g, ln1_b, h, tokens, tok_emb, pos_emb);

    for (int l = 0; l < NLAYER; ++l) {
        // fused QKV: 128x128 tile, grid 16x24 = 384 blocks
        gemm_tiled<128, 128, 64, 1, 0, 0><<<dim3(16, 24), blk256, 0, stream>>>(
            h, wqkv_t + (size_t)l * 3072 * 1024, S_LEN, 3072, 1024,
            nullptr, nullptr, nullptr, qbuf, kbuf, vbuf,
            bq + l * 1024, bk + l * 1024, bv + l * 1024);
        attn_kernel<<<dim3(32, NHEAD), blk256, 0, stream>>>(
            qbuf, kbuf, vbuf, ctx);
        // proj: split-K x2 -> f32 partials into pproj (ffn region)
        gemm_tiled<64, 128, 64, 2, 6, 0><<<dim3(32, 8, 2), blk256, 0, stream>>>(
            ctx, wo_t + (size_t)l * 1024 * 1024, S_LEN, 1024, 1024,
            bo + l * 1024, pproj, nullptr, nullptr, nullptr, nullptr,
            nullptr, nullptr, nullptr);
        // ln2 fuses x += pproj0 + pproj1
        ln_kernel<2, 0><<<dim3(S_LEN), blk256, 0, stream>>>(
            x, pproj, ln2_g + l * 1024, ln2_b + l * 1024, h,
            nullptr, nullptr, nullptr);
        // FFN1: 128x128, grid 16x32 = 512 blocks
        gemm_tiled<128, 128, 64, 1, 2, 0><<<dim3(16, 32), blk256, 0, stream>>>(
            h, w1_t + (size_t)l * 4096 * 1024, S_LEN, 4096, 1024,
            b1 + l * 4096, nullptr, ffn, nullptr, nullptr, nullptr,
            nullptr, nullptr, nullptr);
        // FFN2: split-K x2 -> f32 partials into pffn2 (qkv/ctx region)
        gemm_tiled<64, 128, 64, 2, 6, 0><<<dim3(32, 8, 2), blk256, 0, stream>>>(
            ffn, w2_t + (size_t)l * 1024 * 4096, S_LEN, 1024, 4096,
            b2 + l * 1024, pffn2, nullptr, nullptr, nullptr, nullptr,
            nullptr, nullptr, nullptr);
        // next LN fuses x += pffn2_0 + pffn2_1
        if (l + 1 < NLAYER) {
            ln_kernel<2, 0><<<dim3(S_LEN), blk256, 0, stream>>>(
                x, pffn2, ln1_g + (l + 1) * 1024, ln1_b + (l + 1) * 1024, h,
                nullptr, nullptr, nullptr);
        }
    }

    ln_kernel<2, 0><<<dim3(S_LEN), blk256, 0, stream>>>(
        x, pffn2, lnf_g, lnf_b, h, nullptr, nullptr, nullptr);
    // logits: 256x256 8-phase rotated-quadrant kernel, grid 1000 (8M x 125N)
    gemm_logits_8r<<<dim3(1000), dim3(512), 0, stream>>>(
        h, temb, (float*)d_out);
}

// Round 17
// 1595.969 us; speedup vs baseline: 1.0233x; 1.0233x over previous
//
#include <hip/hip_runtime.h>
#include <hip/hip_bf16.h>
#include <cstdint>
#include <cstddef>

// ---------------------------------------------------------------------------
// MiniGPT forward on MI355X (gfx950).  Round 17: best-known configuration.
//  - logits: REVERTED to the proven 2-phase gemm_tiled<128,256,32,1,3,1>
//    (213 us measured; three derived 8-phase ports all slower or wrong).
//  - gemm_tiled: two-barrier counted-vmcnt (round-9 schedule).
//  - attention: KVBLK=128, XCD head-clustering, complementary rowgroups,
//    exp2 softmax.
//  - split-K proj/FFN2 -> f32 NT partials + fused-add LN; fused embed+LN.
// MODES: 0 QKV-split  2 GELU->bf16  3 f32 NT store  6 f32 NT partial (+bias@kz0)
// ---------------------------------------------------------------------------

typedef __attribute__((ext_vector_type(4))) float  f32x4;
typedef __attribute__((ext_vector_type(8))) __bf16 bf16x8;
typedef __attribute__((ext_vector_type(4))) __bf16 bf16x4;

#define S_LEN 2048
#define DMODEL 1024
#define DFF 4096
#define NLAYER 6
#define NHEAD 16
#define DK 64
#define VOCAB 32000
#define MN (S_LEN * DMODEL)

__device__ __forceinline__ void gload_lds16(const void* g, void* l) {
    __builtin_amdgcn_global_load_lds(
        (__attribute__((address_space(1))) void*)(void*)(g),
        (__attribute__((address_space(3))) void*)(l), 16, 0, 0);
}

// ---------------------------------------------------------------------------
// 64x64 transpose+cvt body (shared).
// ---------------------------------------------------------------------------
__device__ __forceinline__ void tr64_body(
    const float* __restrict__ inp, __bf16* __restrict__ outp,
    int K, int N, int n0, int k0, int t) {
    __shared__ float tile[64][65];
    const int lc = t & 15, rr = t >> 4;
#pragma unroll
    for (int i = 0; i < 4; ++i) {
        float4 v = *(const float4*)&inp[(size_t)(k0 + rr + i * 16) * N + n0 + lc * 4];
        tile[rr + i * 16][lc * 4 + 0] = v.x;
        tile[rr + i * 16][lc * 4 + 1] = v.y;
        tile[rr + i * 16][lc * 4 + 2] = v.z;
        tile[rr + i * 16][lc * 4 + 3] = v.w;
    }
    __syncthreads();
    const int a = t & 7, b = t >> 3;
#pragma unroll
    for (int j = 0; j < 2; ++j) {
        const int n = b + j * 32;
        bf16x8 o;
#pragma unroll
        for (int e = 0; e < 8; ++e) o[e] = (__bf16)tile[a * 8 + e][n];
        *(bf16x8*)&outp[(size_t)(n0 + n) * K + k0 + a * 8] = o;
    }
}

__global__ __launch_bounds__(256) void transpose_cvt64(
    const float* __restrict__ in, __bf16* __restrict__ out,
    int K, int N, size_t in_lstride, size_t out_lstride) {
    tr64_body(in + blockIdx.z * in_lstride, out + blockIdx.z * out_lstride,
              K, N, blockIdx.x * 64, blockIdx.y * 64, threadIdx.x);
}

// batched Wq/Wk/Wv/Wo transpose: grid (16,16,4*NLAYER); z -> (mat, layer)
__global__ __launch_bounds__(256) void transpose_qkvo(
    const float* __restrict__ Wq, const float* __restrict__ Wk,
    const float* __restrict__ Wv, const float* __restrict__ Wo,
    __bf16* __restrict__ wqkv_t, __bf16* __restrict__ wo_t) {
    const int z = blockIdx.z, mat = z & 3, l = z >> 2;
    const float* src =
        (mat == 0 ? Wq : mat == 1 ? Wk : mat == 2 ? Wv : Wo) +
        (size_t)l * 1024 * 1024;
    __bf16* dst = (mat < 3)
        ? wqkv_t + (size_t)l * 3072 * 1024 + (size_t)mat * 1024 * 1024
        : wo_t + (size_t)l * 1024 * 1024;
    tr64_body(src, dst, 1024, 1024, blockIdx.x * 64, blockIdx.y * 64, threadIdx.x);
}

__global__ __launch_bounds__(256) void cvt_bf16(
    const float* __restrict__ in, __bf16* __restrict__ out, long n4) {
    long i = (long)blockIdx.x * 256 + threadIdx.x;
    if (i >= n4) return;
    float4 v = ((const float4*)in)[i];
    bf16x4 o = {(__bf16)v.x, (__bf16)v.y, (__bf16)v.z, (__bf16)v.w};
    ((bf16x4*)out)[i] = o;
}

// ---------------------------------------------------------------------------
// LayerNorm family.  EMBED: x = tok_emb[tok]+pos_emb first.  NPART=2: fuse
// x += p[row] + p[MN+row] first.  f32 in, bf16 out.  grid = rows, block 256.
// ---------------------------------------------------------------------------
template <int NPART, int EMBED>
__global__ __launch_bounds__(256) void ln_kernel(
    float* __restrict__ x, const float* __restrict__ p,
    const float* __restrict__ g, const float* __restrict__ b,
    __bf16* __restrict__ out,
    const int* __restrict__ tokens, const float* __restrict__ te,
    const float* __restrict__ pe) {
    const int row = blockIdx.x, t = threadIdx.x;
    float4 v;
    if (EMBED) {
        const int tok = tokens[row];
        float4 a = ((const float4*)(te + (size_t)tok * DMODEL))[t];
        float4 q = ((const float4*)(pe + (size_t)row * DMODEL))[t];
        v = float4{a.x + q.x, a.y + q.y, a.z + q.z, a.w + q.w};
        ((float4*)(x + (size_t)row * DMODEL))[t] = v;
    } else {
        v = ((const float4*)(x + (size_t)row * DMODEL))[t];
    }
    if (NPART == 2) {
        float4 a0 = ((const float4*)(p + (size_t)row * DMODEL))[t];
        float4 a1 = ((const float4*)(p + MN + (size_t)row * DMODEL))[t];
        v.x += a0.x + a1.x;
        v.y += a0.y + a1.y;
        v.z += a0.z + a1.z;
        v.w += a0.w + a1.w;
        ((float4*)(x + (size_t)row * DMODEL))[t] = v;
    }
    float s  = v.x + v.y + v.z + v.w;
    float s2 = v.x * v.x + v.y * v.y + v.z * v.z + v.w * v.w;
#pragma unroll
    for (int off = 1; off < 64; off <<= 1) {
        s  += __shfl_xor(s, off);
        s2 += __shfl_xor(s2, off);
    }
    __shared__ float ss[4], ss2[4];
    const int wave = t >> 6;
    if ((t & 63) == 0) { ss[wave] = s; ss2[wave] = s2; }
    __syncthreads();
    s  = ss[0] + ss[1] + ss[2] + ss[3];
    s2 = ss2[0] + ss2[1] + ss2[2] + ss2[3];
    const float mu  = s * (1.0f / DMODEL);
    const float var = s2 * (1.0f / DMODEL) - mu * mu;
    const float rstd = rsqrtf(var + 1e-5f);
    float4 gg = ((const float4*)g)[t];
    float4 bb = ((const float4*)b)[t];
    __bf16* o = out + (size_t)row * DMODEL + t * 4;
    o[0] = (__bf16)((v.x - mu) * rstd * gg.x + bb.x);
    o[1] = (__bf16)((v.y - mu) * rstd * gg.y + bb.y);
    o[2] = (__bf16)((v.z - mu) * rstd * gg.z + bb.z);
    o[3] = (__bf16)((v.w - mu) * rstd * gg.w + bb.w);
}

// ---------------------------------------------------------------------------
// gemm_tiled<BM,BN,BK,SPLITK,MODE,XCD>: two-barrier counted-vmcnt (round-9).
// Both-sides XOR swizzle: phys_slot = slot ^ ((row >> SH) & (SLOTS-1)).
// ---------------------------------------------------------------------------
template <int BM, int BN, int BK, int SPLITK, int MODE, int XCD>
__global__ __launch_bounds__(256) void gemm_tiled(
    const __bf16* __restrict__ A, const __bf16* __restrict__ BT,
    int M, int N, int K,
    const float* __restrict__ bias,
    float* __restrict__ fout,
    __bf16* __restrict__ bfout,
    __bf16* __restrict__ qb, __bf16* __restrict__ kb, __bf16* __restrict__ vb,
    const float* __restrict__ bq, const float* __restrict__ bk,
    const float* __restrict__ bv) {
    constexpr int SLOTS = BK / 8;
    constexpr int SH    = (BK == 64) ? 0 : 1;
    constexpr int RPC   = 2048 / BK;
    constexpr int ACH_A = BM / RPC;
    constexpr int ACH_B = BN / RPC;
    constexpr int LOADS = ACH_A + ACH_B;
    constexpr int MR = BM / 32;
    constexpr int NR = BN / 32;
    constexpr int KS = BK / 32;
    __shared__ alignas(16) __bf16 As[2][BM * BK];
    __shared__ alignas(16) __bf16 Bs[2][BN * BK];
    const int t = threadIdx.x;
    const int wave = t >> 6, lane = t & 63;
    const int wr = wave >> 1, wc = wave & 1;
    const int lg = lane >> 4, lr = lane & 15;

    int bx = blockIdx.x, by = blockIdx.y;
    if (XCD) {
        const int nwg = gridDim.x * gridDim.y;
        const int wgid = by * gridDim.x + bx;
        const int sw = (wgid & 7) * (nwg >> 3) + (wgid >> 3);
        bx = sw % gridDim.x;
        by = sw / gridDim.x;
    }
    const int row0 = bx * BM, col0 = by * BN;
    const int kz = (SPLITK > 1) ? blockIdx.z : 0;
    const int Ksl = K / SPLITK;

    f32x4 acc[MR][NR];
#pragma unroll
    for (int i = 0; i < MR; i++)
#pragma unroll
        for (int j = 0; j < NR; j++) acc[i][j] = f32x4{0.f, 0.f, 0.f, 0.f};

    const int srow = t / SLOTS;
    const int sks = ((t % SLOTS) ^ ((srow >> SH) & (SLOTS - 1))) * 8;
    const __bf16* Ab = A + (size_t)(row0 + srow) * K + kz * Ksl + sks;
    const __bf16* Bb = BT + (size_t)(col0 + srow) * K + kz * Ksl + sks;

    const int nt = Ksl / BK;
#pragma unroll
    for (int ch = 0; ch < ACH_A; ++ch)
        gload_lds16(Ab + (size_t)ch * RPC * K, &As[0][ch * 2048 + wave * 512]);
#pragma unroll
    for (int ch = 0; ch < ACH_B; ++ch)
        gload_lds16(Bb + (size_t)ch * RPC * K, &Bs[0][ch * 2048 + wave * 512]);

    int c = 0;
    for (int T = 0; T < nt; ++T) {
        if (T + 1 < nt) {
            const int k0 = (T + 1) * BK;
#pragma unroll
            for (int ch = 0; ch < ACH_A; ++ch)
                gload_lds16(Ab + (size_t)ch * RPC * K + k0,
                            &As[c ^ 1][ch * 2048 + wave * 512]);
#pragma unroll
            for (int ch = 0; ch < ACH_B; ++ch)
                gload_lds16(Bb + (size_t)ch * RPC * K + k0,
                            &Bs[c ^ 1][ch * 2048 + wave * 512]);
            if constexpr (LOADS == 3)
                asm volatile("s_waitcnt vmcnt(3)" ::: "memory");
            else if constexpr (LOADS == 4)
                asm volatile("s_waitcnt vmcnt(4)" ::: "memory");
            else if constexpr (LOADS == 6)
                asm volatile("s_waitcnt vmcnt(6)" ::: "memory");
            else
                asm volatile("s_waitcnt vmcnt(8)" ::: "memory");
        } else {
            asm volatile("s_waitcnt vmcnt(0)" ::: "memory");
        }
        __builtin_amdgcn_s_barrier();
        asm volatile("" ::: "memory");

        bf16x8 af[MR][KS], bfr[NR][KS];
#pragma unroll
        for (int i = 0; i < MR; i++)
#pragma unroll
            for (int ks = 0; ks < KS; ks++) {
                const int row = wr * (BM / 2) + i * 16 + lr;
                const int ph = ((ks * 4 + lg) ^ ((row >> SH) & (SLOTS - 1)));
                af[i][ks] = *(const bf16x8*)&As[c][row * BK + ph * 8];
            }
#pragma unroll
        for (int j = 0; j < NR; j++)
#pragma unroll
            for (int ks = 0; ks < KS; ks++) {
                const int n = wc * (BN / 2) + j * 16 + lr;
                const int ph = ((ks * 4 + lg) ^ ((n >> SH) & (SLOTS - 1)));
                bfr[j][ks] = *(const bf16x8*)&Bs[c][n * BK + ph * 8];
            }
        __builtin_amdgcn_s_setprio(1);
#pragma unroll
        for (int i = 0; i < MR; i++)
#pragma unroll
            for (int j = 0; j < NR; j++)
#pragma unroll
                for (int ks = 0; ks < KS; ks++)
                    acc[i][j] = __builtin_amdgcn_mfma_f32_16x16x32_bf16(
                        af[i][ks], bfr[j][ks], acc[i][j], 0, 0, 0);
        __builtin_amdgcn_s_setprio(0);
        asm volatile("" ::: "memory");
        __builtin_amdgcn_s_barrier();
        c ^= 1;
    }

#pragma unroll
    for (int i = 0; i < MR; i++) {
#pragma unroll
        for (int j = 0; j < NR; j++) {
#pragma unroll
            for (int r = 0; r < 4; r++) {
                const int row = row0 + wr * (BM / 2) + i * 16 + lg * 4 + r;
                const int col = col0 + wc * (BN / 2) + j * 16 + lr;
                float v = acc[i][j][r];
                if (MODE == 0) {          // fused QKV split epilogue
                    const int sec = col >> 10, cn = col & 1023;
                    const int head = cn >> 6, d = cn & 63;
                    if (sec == 0) {
                        // fold 1/sqrt(dk) * log2(e): softmax in exp2 domain
                        v = (v + bq[cn]) * 0.18033688011112042f;
                        qb[((size_t)head * S_LEN + row) * DK + d] = (__bf16)v;
                    } else if (sec == 1) {
                        v = v + bk[cn];
                        kb[((size_t)head * S_LEN + row) * DK + d] = (__bf16)v;
                    } else {
                        v = v + bv[cn];
                        vb[((size_t)head * DK + d) * S_LEN + row] = (__bf16)v;
                    }
                } else if (MODE == 2) {
                    const float gg = v + bias[col];
                    const float cgl = 0.5f * gg * (1.0f + erff(gg * 0.70710678118654752f));
                    bfout[(size_t)row * N + col] = (__bf16)cgl;
                } else if (MODE == 6) {   // split-K partial, bias on slice 0
                    const float vv = v + (kz == 0 ? bias[col] : 0.f);
                    __builtin_nontemporal_store(
                        vv, &fout[(size_t)kz * MN + (size_t)row * N + col]);
                } else {                  // MODE 3: plain f32 NT store
                    __builtin_nontemporal_store(v, &fout[(size_t)row * N + col]);
                }
            }
        }
    }
}

// ---------------------------------------------------------------------------
// Flash attention (causal).  grid (32, NHEAD), block 256 (4 independent
// waves).  XCD head-clustering (each XCD owns 2 heads -> K/V L2-resident).
// Wave w handles q-rowgroup {2x,2x+1,126-2x,127-2x}[w] -> uniform work.
// KVBLK=128; scores pre-scaled by log2e/8 -> exp2 softmax.
// ---------------------------------------------------------------------------
__global__ __launch_bounds__(256) void attn_kernel(
    const __bf16* __restrict__ q, const __bf16* __restrict__ k,
    const __bf16* __restrict__ vt, __bf16* __restrict__ ctx) {
    const int lin = blockIdx.y * 32 + blockIdx.x;
    const int u = (lin & 7) * 64 + (lin >> 3);   // XCD c -> heads {2c, 2c+1}
    const int head = u >> 5, xb = u & 31;
    const int t = threadIdx.x;
    const int wave = t >> 6, lane = t & 63;
    const int lg = lane >> 4, lr = lane & 15;
    const int rg = (wave < 2) ? (2 * xb + wave) : (127 - 2 * xb - (3 - wave));
    const int rowbase = rg * 16;
    const int tend = rg >> 3;

    const __bf16* qh = q + (size_t)head * S_LEN * DK;
    const __bf16* kh = k + (size_t)head * S_LEN * DK;
    const __bf16* vh = vt + (size_t)head * DK * S_LEN;

    __shared__ alignas(16) __bf16 pls[4][16 * 136];
    __bf16* pw = pls[wave];

    bf16x8 qf0 = *(const bf16x8*)&qh[(size_t)(rowbase + lr) * DK + lg * 8];
    bf16x8 qf1 = *(const bf16x8*)&qh[(size_t)(rowbase + lr) * DK + 32 + lg * 8];

    f32x4 oacc[4];
#pragma unroll
    for (int j = 0; j < 4; j++) oacc[j] = f32x4{0.f, 0.f, 0.f, 0.f};
    float m[4], l[4];
#pragma unroll
    for (int r = 0; r < 4; r++) { m[r] = -__builtin_inff(); l[r] = 0.f; }

    for (int tt = 0; tt <= tend; ++tt) {
        const int kv0 = tt * 128;
        f32x4 sc[8];
        __builtin_amdgcn_s_setprio(1);
#pragma unroll
        for (int jn = 0; jn < 8; jn++) {
            bf16x8 kf0 = *(const bf16x8*)&kh[(size_t)(kv0 + jn * 16 + lr) * DK + lg * 8];
            bf16x8 kf1 = *(const bf16x8*)&kh[(size_t)(kv0 + jn * 16 + lr) * DK + 32 + lg * 8];
            sc[jn] = __builtin_amdgcn_mfma_f32_16x16x32_bf16(
                qf0, kf0, f32x4{0.f, 0.f, 0.f, 0.f}, 0, 0, 0);
            sc[jn] = __builtin_amdgcn_mfma_f32_16x16x32_bf16(qf1, kf1, sc[jn], 0, 0, 0);
        }
        __builtin_amdgcn_s_setprio(0);

        if (tt == tend) {
#pragma unroll
            for (int jn = 0; jn < 8; jn++)
#pragma unroll
                for (int r = 0; r < 4; r++) {
                    const int qrow = rowbase + lg * 4 + r;
                    if (kv0 + jn * 16 + lr > qrow) sc[jn][r] = -__builtin_inff();
                }
        }

        float mt[4];
#pragma unroll
        for (int r = 0; r < 4; r++) {
            float a0 = fmaxf(fmaxf(sc[0][r], sc[1][r]), fmaxf(sc[2][r], sc[3][r]));
            float a1 = fmaxf(fmaxf(sc[4][r], sc[5][r]), fmaxf(sc[6][r], sc[7][r]));
            mt[r] = fmaxf(a0, a1);
        }
#pragma unroll
        for (int off = 1; off < 16; off <<= 1)
#pragma unroll
            for (int r = 0; r < 4; r++) mt[r] = fmaxf(mt[r], __shfl_xor(mt[r], off));

        float alpha[4], psum[4];
#pragma unroll
        for (int r = 0; r < 4; r++) {
            const float mn = fmaxf(m[r], mt[r]);
            alpha[r] = exp2f(m[r] - mn);
            m[r] = mn;
#pragma unroll
            for (int jn = 0; jn < 8; jn++) sc[jn][r] = exp2f(sc[jn][r] - mn);
            psum[r] = ((sc[0][r] + sc[1][r]) + (sc[2][r] + sc[3][r])) +
                      ((sc[4][r] + sc[5][r]) + (sc[6][r] + sc[7][r]));
        }
#pragma unroll
        for (int off = 1; off < 16; off <<= 1)
#pragma unroll
            for (int r = 0; r < 4; r++) psum[r] += __shfl_xor(psum[r], off);
#pragma unroll
        for (int r = 0; r < 4; r++) l[r] = l[r] * alpha[r] + psum[r];
#pragma unroll
        for (int j = 0; j < 4; j++)
#pragma unroll
            for (int r = 0; r < 4; r++) oacc[j][r] *= alpha[r];

#pragma unroll
        for (int r = 0; r < 4; r++)
#pragma unroll
            for (int jn = 0; jn < 8; jn++)
                pw[(lg * 4 + r) * 136 + jn * 16 + lr] = (__bf16)sc[jn][r];

        bf16x8 pf[4];
#pragma unroll
        for (int h = 0; h < 4; h++)
            pf[h] = *(const bf16x8*)&pw[lr * 136 + h * 32 + lg * 8];
        __builtin_amdgcn_s_setprio(1);
#pragma unroll
        for (int j = 0; j < 4; j++) {
#pragma unroll
            for (int h = 0; h < 4; h++) {
                bf16x8 vf = *(const bf16x8*)
                    &vh[(size_t)(j * 16 + lr) * S_LEN + kv0 + h * 32 + lg * 8];
                oacc[j] = __builtin_amdgcn_mfma_f32_16x16x32_bf16(
                    pf[h], vf, oacc[j], 0, 0, 0);
            }
        }
        __builtin_amdgcn_s_setprio(0);
    }

#pragma unroll
    for (int j = 0; j < 4; j++)
#pragma unroll
        for (int r = 0; r < 4; r++) {
            const int row = rowbase + lg * 4 + r;
            ctx[(size_t)row * DMODEL + head * DK + j * 16 + lr] =
                (__bf16)(oacc[j][r] / l[r]);
        }
}

// ---------------------------------------------------------------------------
extern "C" void kernel_launch(void* const* d_in, const int* in_sizes, int n_in,
                              void* d_out, int out_size, void* d_ws, size_t ws_size,
                              hipStream_t stream) {
    const int*   tokens  = (const int*)d_in[0];
    const float* tok_emb = (const float*)d_in[1];
    const float* pos_emb = (const float*)d_in[2];
    const float* Wq = (const float*)d_in[3];
    const float* bq = (const float*)d_in[4];
    const float* Wk = (const float*)d_in[5];
    const float* bk = (const float*)d_in[6];
    const float* Wv = (const float*)d_in[7];
    const float* bv = (const float*)d_in[8];
    const float* Wo = (const float*)d_in[9];
    const float* bo = (const float*)d_in[10];
    const float* ln1_g = (const float*)d_in[11];
    const float* ln1_b = (const float*)d_in[12];
    const float* ln2_g = (const float*)d_in[13];
    const float* ln2_b = (const float*)d_in[14];
    const float* W1 = (const float*)d_in[15];
    const float* b1 = (const float*)d_in[16];
    const float* W2 = (const float*)d_in[17];
    const float* b2 = (const float*)d_in[18];
    const float* lnf_g = (const float*)d_in[19];
    const float* lnf_b = (const float*)d_in[20];

    char* ws = (char*)d_ws;
    size_t off = 0;
    auto alloc = [&](size_t bytes) {
        char* p = ws + off;
        off = (off + bytes + 255) & ~(size_t)255;
        return p;
    };
    __bf16* wqkv_t = (__bf16*)alloc((size_t)NLAYER * 3072 * 1024 * 2);
    __bf16* wo_t   = (__bf16*)alloc((size_t)NLAYER * 1024 * 1024 * 2);
    __bf16* w1_t   = (__bf16*)alloc((size_t)NLAYER * 4096 * 1024 * 2);
    __bf16* w2_t   = (__bf16*)alloc((size_t)NLAYER * 1024 * 4096 * 2);
    __bf16* temb   = (__bf16*)alloc((size_t)VOCAB * DMODEL * 2);
    float*  x      = (float*)alloc((size_t)MN * 4);
    __bf16* h      = (__bf16*)alloc((size_t)MN * 2);
    __bf16* qbuf   = (__bf16*)alloc((size_t)MN * 2);
    __bf16* kbuf   = (__bf16*)alloc((size_t)MN * 2);
    __bf16* vbuf   = (__bf16*)alloc((size_t)MN * 2);
    __bf16* ctx    = (__bf16*)alloc((size_t)MN * 2);
    __bf16* ffn    = (__bf16*)alloc((size_t)S_LEN * DFF * 2);
    if (off > ws_size) return;

    // split-K partial overlays (dead regions during their live windows)
    float* pproj  = (float*)ffn;      // dead until FFN1 writes it
    float* pffn2  = (float*)qbuf;     // q/k/v/ctx dead after proj

    const dim3 blk256(256);

    transpose_qkvo<<<dim3(16, 16, 4 * NLAYER), blk256, 0, stream>>>(
        Wq, Wk, Wv, Wo, wqkv_t, wo_t);
    transpose_cvt64<<<dim3(64, 16, NLAYER), blk256, 0, stream>>>(
        W1, w1_t, 1024, 4096, (size_t)1024 * 4096, (size_t)4096 * 1024);
    transpose_cvt64<<<dim3(16, 64, NLAYER), blk256, 0, stream>>>(
        W2, w2_t, 4096, 1024, (size_t)4096 * 1024, (size_t)1024 * 4096);
    cvt_bf16<<<dim3((VOCAB * DMODEL / 4 + 255) / 256), blk256, 0, stream>>>(
        tok_emb, temb, (long)VOCAB * DMODEL / 4);

    // fused embed + LN1(layer 0)
    ln_kernel<0, 1><<<dim3(S_LEN), blk256, 0, stream>>>(
        x, nullptr, ln1_g, ln1_b, h, tokens, tok_emb, pos_emb);

    for (int l = 0; l < NLAYER; ++l) {
        // fused QKV: 128x128 tile, grid 16x24 = 384 blocks
        gemm_tiled<128, 128, 64, 1, 0, 0><<<dim3(16, 24), blk256, 0, stream>>>(
            h, wqkv_t + (size_t)l * 3072 * 1024, S_LEN, 3072, 1024,
            nullptr, nullptr, nullptr, qbuf, kbuf, vbuf,
            bq + l * 1024, bk + l * 1024, bv + l * 1024);
        attn_kernel<<<dim3(32, NHEAD), blk256, 0, stream>>>(
            qbuf, kbuf, vbuf, ctx);
        // proj: split-K x2 -> f32 partials into pproj (ffn region)
        gemm_tiled<64, 128, 64, 2, 6, 0><<<dim3(32, 8, 2), blk256, 0, stream>>>(
            ctx, wo_t + (size_t)l * 1024 * 1024, S_LEN, 1024, 1024,
            bo + l * 1024, pproj, nullptr, nullptr, nullptr, nullptr,
            nullptr, nullptr, nullptr);
        // ln2 fuses x += pproj0 + pproj1
        ln_kernel<2, 0><<<dim3(S_LEN), blk256, 0, stream>>>(
            x, pproj, ln2_g + l * 1024, ln2_b + l * 1024, h,
            nullptr, nullptr, nullptr);
        // FFN1: 128x128, grid 16x32 = 512 blocks
        gemm_tiled<128, 128, 64, 1, 2, 0><<<dim3(16, 32), blk256, 0, stream>>>(
            h, w1_t + (size_t)l * 4096 * 1024, S_LEN, 4096, 1024,
            b1 + l * 4096, nullptr, ffn, nullptr, nullptr, nullptr,
            nullptr, nullptr, nullptr);
        // FFN2: split-K x2 -> f32 partials into pffn2 (qkv/ctx region)
        gemm_tiled<64, 128, 64, 2, 6, 0><<<dim3(32, 8, 2), blk256, 0, stream>>>(
            ffn, w2_t + (size_t)l * 1024 * 4096, S_LEN, 1024, 4096,
            b2 + l * 1024, pffn2, nullptr, nullptr, nullptr, nullptr,
            nullptr, nullptr, nullptr);
        // next LN fuses x += pffn2_0 + pffn2_1
        if (l + 1 < NLAYER) {
            ln_kernel<2, 0><<<dim3(S_LEN), blk256, 0, stream>>>(
                x, pffn2, ln1_g + (l + 1) * 1024, ln1_b + (l + 1) * 1024, h,
                nullptr, nullptr, nullptr);
        }
    }

    ln_kernel<2, 0><<<dim3(S_LEN), blk256, 0, stream>>>(
        x, pffn2, lnf_g, lnf_b, h, nullptr, nullptr, nullptr);
    // logits: 128x256 BK=32 2-phase tile, grid 16x125 = 2000 blocks,
    // XCD-chunked swizzle (proven 213 us)
    gemm_tiled<128, 256, 32, 1, 3, 1><<<dim3(16, 125), blk256, 0, stream>>>(
        h, temb, S_LEN, VOCAB, 1024,
        nullptr, (float*)d_out, nullptr, nullptr, nullptr, nullptr,
        nullptr, nullptr, nullptr);
}